// Round 10
// baseline (36.038 us; speedup 1.0000x reference)
//
#include <hip/hip_runtime.h>
#include <math.h>

// Problem constants: B=256, N=64, M=64, d=32, TOPK=10
constexpr int Bn = 256;
constexpr int Nn = 64;
constexpr int Mn = 64;
constexpr int Dn = 32;
constexpr int TK = 10;

// Correctly-rounded fp32 exp via fp64 (matches np within <=0.5 ulp)
__device__ __forceinline__ float exp_np(float x) {
    return (float)exp((double)x);
}
// Monotone fp32 -> uint32 order map (weights finite; no NaNs)
__device__ __forceinline__ unsigned int f2u(float f) {
    unsigned int b = __float_as_uint(f);
    return (b & 0x80000000u) ? ~b : (b | 0x80000000u);
}
__device__ __forceinline__ float u2f(unsigned int u) {
    return __uint_as_float((u & 0x80000000u) ? (u ^ 0x80000000u) : ~u);
}

// ============================================================================
// Kernel A: per-batch  K-softmax, V, Q, lam.  Writes Q ([k][n] 32x64) and
// lam ([k][v] 32x64) to ws at ws[b*4096] / ws[b*4096+2048].
// Arithmetic chains identical to the passing r9 kernel (bit-exact).
// ============================================================================
__global__ __launch_bounds__(1024) void lam_kernel(
    const float* __restrict__ fv, const float* __restrict__ cv,
    const float* __restrict__ Wq, const float* __restrict__ Wk,
    const float* __restrict__ Wv, float* __restrict__ ws)
{
    #pragma clang fp contract(off)

    __shared__ float fT[Dn][65];    // [d][n]
    __shared__ float cT[Dn][65];    // [d][m]
    __shared__ float KpT[Dn][68];   // [k][m] K probabilities
    __shared__ float VwS[Mn][68];   // [m][v] V

    const int b    = blockIdx.x;
    const int tid  = threadIdx.x;
    const int lane = tid & 63;
    const int wid  = tid >> 6;

    float* wsQ = ws + (size_t)b * 4096;
    float* wsL = wsQ + 2048;

    // ---- stage: f -> fT, c -> cT (coalesced f4 global reads, transposed LDS scatter) ----
    if (tid < 512) {
        const float4 v = reinterpret_cast<const float4*>(fv + (size_t)b * Nn * Dn)[tid];
        const int n = tid >> 3, d4 = (tid & 7) << 2;
        fT[d4 + 0][n] = v.x; fT[d4 + 1][n] = v.y; fT[d4 + 2][n] = v.z; fT[d4 + 3][n] = v.w;
    } else {
        const int t = tid - 512;
        const float4 v = reinterpret_cast<const float4*>(cv + (size_t)b * Mn * Dn)[t];
        const int m = t >> 3, d4 = (t & 7) << 2;
        cT[d4 + 0][m] = v.x; cT[d4 + 1][m] = v.y; cT[d4 + 2][m] = v.z; cT[d4 + 3][m] = v.w;
    }
    __syncthreads();

    // ---- Phase A: K+softmax on waves 0-7; Q and V on waves 8-15.
    // W matrices via wave-uniform pointers -> scalar cache (s_load).
    if (wid < 8) {
        // K columns 4w..4w+3; lane = m. Sequential ascending-d mul-then-add (np-exact).
        const int kq = __builtin_amdgcn_readfirstlane(wid);
        const int m = lane;
        const float* wkq = Wk + (kq << 2);
        float a0 = 0.f, a1 = 0.f, a2 = 0.f, a3 = 0.f;
        #pragma unroll 4
        for (int d = 0; d < Dn; ++d) {
            const float cc = cT[d][m];
            const float* wr = wkq + d * Dn;
            const float w0 = wr[0], w1 = wr[1], w2 = wr[2], w3 = wr[3];
            a0 = a0 + cc * w0;  a1 = a1 + cc * w1;  a2 = a2 + cc * w2;  a3 = a3 + cc * w3;
        }
        // column max: xor shuffle tree (fmax exactly order-independent)
        float m0 = a0, m1 = a1, m2 = a2, m3 = a3;
        #pragma unroll
        for (int off = 1; off < 64; off <<= 1) {
            m0 = fmaxf(m0, __shfl_xor(m0, off));
            m1 = fmaxf(m1, __shfl_xor(m1, off));
            m2 = fmaxf(m2, __shfl_xor(m2, off));
            m3 = fmaxf(m3, __shfl_xor(m3, off));
        }
        // exp, then ascending-m ordered sum (np.sum order), then true division
        const float e0 = exp_np(a0 - m0);
        const float e1 = exp_np(a1 - m1);
        const float e2 = exp_np(a2 - m2);
        const float e3 = exp_np(a3 - m3);
        float s0 = 0.f, s1 = 0.f, s2 = 0.f, s3 = 0.f;
        #pragma unroll
        for (int t = 0; t < 64; ++t) {
            s0 = s0 + __shfl(e0, t);
            s1 = s1 + __shfl(e1, t);
            s2 = s2 + __shfl(e2, t);
            s3 = s3 + __shfl(e3, t);
        }
        KpT[(kq << 2) + 0][m] = e0 / s0;
        KpT[(kq << 2) + 1][m] = e1 / s1;
        KpT[(kq << 2) + 2][m] = e2 / s2;
        KpT[(kq << 2) + 3][m] = e3 / s3;
    } else {
        // Q columns 4q..4q+3 (-> global ws, coalesced) AND V columns 8q..8q+7 (-> LDS)
        const int q = __builtin_amdgcn_readfirstlane(wid - 8);
        const int nm = lane;
        const float* wqq = Wq + (q << 2);
        const float* wvq = Wv + (q << 3);
        float a0 = 0.f, a1 = 0.f, a2 = 0.f, a3 = 0.f;
        float b0 = 0.f, b1 = 0.f, b2 = 0.f, b3 = 0.f, b4 = 0.f, b5 = 0.f, b6 = 0.f, b7 = 0.f;
        #pragma unroll 4
        for (int d = 0; d < Dn; ++d) {
            const float ff = fT[d][nm];
            const float cc = cT[d][nm];
            const float* wr = wqq + d * Dn;
            const float* ur = wvq + d * Mn;
            const float w0 = wr[0], w1 = wr[1], w2 = wr[2], w3 = wr[3];
            const float u0 = ur[0], u1 = ur[1], u2 = ur[2], u3 = ur[3];
            const float u4 = ur[4], u5 = ur[5], u6 = ur[6], u7 = ur[7];
            a0 = a0 + ff * w0;  a1 = a1 + ff * w1;  a2 = a2 + ff * w2;  a3 = a3 + ff * w3;
            b0 = b0 + cc * u0;  b1 = b1 + cc * u1;  b2 = b2 + cc * u2;  b3 = b3 + cc * u3;
            b4 = b4 + cc * u4;  b5 = b5 + cc * u5;  b6 = b6 + cc * u6;  b7 = b7 + cc * u7;
        }
        // Q -> global ws [k][n], one 256B-coalesced store per column
        wsQ[((q << 2) + 0) * 64 + nm] = a0;
        wsQ[((q << 2) + 1) * 64 + nm] = a1;
        wsQ[((q << 2) + 2) * 64 + nm] = a2;
        wsQ[((q << 2) + 3) * 64 + nm] = a3;
        float4 r0; r0.x = b0; r0.y = b1; r0.z = b2; r0.w = b3;
        float4 r1; r1.x = b4; r1.y = b5; r1.z = b6; r1.w = b7;
        *reinterpret_cast<float4*>(&VwS[nm][(q << 3) + 0]) = r0;
        *reinterpret_cast<float4*>(&VwS[nm][(q << 3) + 4]) = r1;
    }
    __syncthreads();

    // ---- lam[k][v] = sum_m K[m][k]*V[m][v]: 1024 threads, (k, v2); store direct to ws ----
    {
        const int k = tid >> 5;
        const int v2 = (tid & 31) << 1;
        float a0 = 0.f, a1 = 0.f;
        for (int m = 0; m < Mn; ++m) {
            const float kk = KpT[k][m];
            const float2 vv = *reinterpret_cast<const float2*>(&VwS[m][v2]);
            a0 = a0 + kk * vv.x;  a1 = a1 + kk * vv.y;
        }
        float2 r; r.x = a0; r.y = a1;
        *reinterpret_cast<float2*>(&wsL[k * 64 + v2]) = r;
    }
}

// ============================================================================
// Kernel B: per (batch, 16-row slice): weight = Q·lam, fused top-10 (+softmax),
// output gather.  Grid = 1024 blocks -> 4 blocks/CU for latency overlap.
// ============================================================================
__global__ __launch_bounds__(256) void out_kernel(
    const float* __restrict__ fv, const float* __restrict__ cv,
    const float* __restrict__ ws, float* __restrict__ out)
{
    #pragma clang fp contract(off)

    __shared__ float lamB[Dn][64];   // [k][v] 8 KB
    __shared__ float QsT[Dn][17];    // [k][n_local] 2.1 KB
    __shared__ float c_r[Mn][36];    // [m][d] padded 9 KB
    __shared__ float f_r[16][36];    // [n_local][d] padded 2.25 KB
    __shared__ float topw[16][TK];
    __shared__ int   topi[16][TK];

    const int bid = blockIdx.x;
    const int b   = bid >> 2;
    const int n0  = (bid & 3) << 4;
    const int tid = threadIdx.x;
    const int lane = tid & 63;

    const float* wsQ = ws + (size_t)b * 4096;
    const float* wsL = wsQ + 2048;

    // ---- stage ----
    {
        const float4* L4 = reinterpret_cast<const float4*>(wsL);
        float4* D4 = reinterpret_cast<float4*>(&lamB[0][0]);
        D4[tid]       = L4[tid];
        D4[tid + 256] = L4[tid + 256];
    }
    {
        const float4* C4 = reinterpret_cast<const float4*>(cv + (size_t)b * Mn * Dn);
        #pragma unroll
        for (int p = 0; p < 2; ++p) {
            const int i = tid + (p << 8);
            const float4 v = C4[i];
            const int m = i >> 3, d4 = (i & 7) << 2;
            *reinterpret_cast<float4*>(&c_r[m][d4]) = v;
        }
    }
    {
        #pragma unroll
        for (int p = 0; p < 2; ++p) {
            const int i = tid + (p << 8);
            const int k = i >> 4, j = i & 15;
            QsT[k][j] = wsQ[k * 64 + n0 + j];
        }
    }
    if (tid < 128) {
        const float4 v = reinterpret_cast<const float4*>(fv + (size_t)b * Nn * Dn + (size_t)n0 * Dn)[tid];
        const int n = tid >> 3, d4 = (tid & 7) << 2;
        *reinterpret_cast<float4*>(&f_r[n][d4]) = v;
    }
    __syncthreads();

    // ---- weight (np-exact ascending-k chain) fused with top-10 selection ----
    {
        const int nl = tid >> 4;     // 0..15
        const int g  = tid & 15;
        const int v4 = g << 2;
        float a0 = 0.f, a1 = 0.f, a2 = 0.f, a3 = 0.f;
        for (int k = 0; k < Dn; ++k) {
            const float qq = QsT[k][nl];
            const float4 lv = *reinterpret_cast<const float4*>(&lamB[k][v4]);
            a0 = a0 + qq * lv.x;  a1 = a1 + qq * lv.y;  a2 = a2 + qq * lv.z;  a3 = a3 + qq * lv.w;
        }

        unsigned su0 = f2u(a0), su1 = f2u(a1), su2 = f2u(a2), su3 = f2u(a3);
        unsigned avail = 0xFu;
        float val0 = 0.f, myval = 0.f;
        int   myidx = 0;

        #pragma unroll
        for (int t = 0; t < TK; ++t) {
            unsigned bu = 0u; int bm = 64;
            if ((avail & 1u) && su0 > bu) { bu = su0; bm = (g << 2) + 0; }
            if ((avail & 2u) && su1 > bu) { bu = su1; bm = (g << 2) + 1; }
            if ((avail & 4u) && su2 > bu) { bu = su2; bm = (g << 2) + 2; }
            if ((avail & 8u) && su3 > bu) { bu = su3; bm = (g << 2) + 3; }
            #pragma unroll
            for (int off = 1; off <= 8; off <<= 1) {
                const unsigned ou = __shfl_xor(bu, off);
                const int      om = __shfl_xor(bm, off);
                if (ou > bu || (ou == bu && om < bm)) { bu = ou; bm = om; }
            }
            const float bv = u2f(bu);
            if (t == 0) val0 = bv;
            if (g == t) { myval = bv; myidx = bm; }
            if ((bm >> 2) == g) avail &= ~(1u << (bm & 3));
        }

        const float ev_own = (g < TK) ? exp_np(myval - val0) : 0.f;
        float s = 0.f;
        #pragma unroll
        for (int t = 0; t < TK; ++t) {
            const float e = __shfl(ev_own, (lane & 48) + t);
            s = s + e;
        }
        if (g < TK) {
            topw[nl][g] = ev_own / s;
            topi[nl][g] = myidx;
        }
    }
    __syncthreads();

    // ---- output: out[b][(n0+n)*TK+t][d] = w * (f[n][d]*c[idx][d]) ----
    float* ob = out + (size_t)b * (Nn * TK * Dn) + (size_t)n0 * (TK * Dn);
    #pragma unroll
    for (int p = 0; p < 5; ++p) {
        const int i = tid + (p << 8);         // 0..1279 f4
        const int n = i / 80;
        const int r = i - n * 80;
        const int t = r >> 3;
        const int d4 = (r & 7) << 2;
        const float w = topw[n][t];
        const int m = topi[n][t];
        const float4 fr = *reinterpret_cast<const float4*>(&f_r[n][d4]);
        const float4 cr = *reinterpret_cast<const float4*>(&c_r[m][d4]);
        float4 o;
        { const float vx = fr.x * cr.x; o.x = w * vx; }
        { const float vy = fr.y * cr.y; o.y = w * vy; }
        { const float vz = fr.z * cr.z; o.z = w * vz; }
        { const float vw = fr.w * cr.w; o.w = w * vw; }
        reinterpret_cast<float4*>(ob)[i] = o;
    }
}

// ============================================================================
// Fallback: r9 monolith (passing), used only if ws_size < 4 MB.
// ============================================================================
__global__ __launch_bounds__(1024) void sparse_lambda_attn_mono(
    const float* __restrict__ fv, const float* __restrict__ cv,
    const float* __restrict__ Wq, const float* __restrict__ Wk,
    const float* __restrict__ Wv, float* __restrict__ out)
{
    #pragma clang fp contract(off)
    __shared__ float fT[Dn][65];
    __shared__ float cT[Dn][65];
    __shared__ float c_lds[Mn][36];
    __shared__ float KpT[Dn][68];
    __shared__ float QmT[Dn][68];
    __shared__ float VwS[Mn][68];
    __shared__ float lamS[Dn][68];
    __shared__ float topw[Nn][TK];
    __shared__ int   topi[Nn][TK];

    const int b    = blockIdx.x;
    const int tid  = threadIdx.x;
    const int lane = tid & 63;
    const int wid  = tid >> 6;

    if (tid < 512) {
        const float4 v = reinterpret_cast<const float4*>(fv + (size_t)b * Nn * Dn)[tid];
        const int n = tid >> 3, d4 = (tid & 7) << 2;
        fT[d4 + 0][n] = v.x; fT[d4 + 1][n] = v.y; fT[d4 + 2][n] = v.z; fT[d4 + 3][n] = v.w;
    } else {
        const int t = tid - 512;
        const float4 v = reinterpret_cast<const float4*>(cv + (size_t)b * Mn * Dn)[t];
        const int m = t >> 3, d4 = (t & 7) << 2;
        *reinterpret_cast<float4*>(&c_lds[m][d4]) = v;
        cT[d4 + 0][m] = v.x; cT[d4 + 1][m] = v.y; cT[d4 + 2][m] = v.z; cT[d4 + 3][m] = v.w;
    }
    __syncthreads();

    if (wid < 8) {
        const int kq = __builtin_amdgcn_readfirstlane(wid);
        const int m = lane;
        const float* wkq = Wk + (kq << 2);
        float a0 = 0.f, a1 = 0.f, a2 = 0.f, a3 = 0.f;
        #pragma unroll 4
        for (int d = 0; d < Dn; ++d) {
            const float cc = cT[d][m];
            const float* wr = wkq + d * Dn;
            const float w0 = wr[0], w1 = wr[1], w2 = wr[2], w3 = wr[3];
            a0 = a0 + cc * w0;  a1 = a1 + cc * w1;  a2 = a2 + cc * w2;  a3 = a3 + cc * w3;
        }
        float m0 = a0, m1 = a1, m2 = a2, m3 = a3;
        #pragma unroll
        for (int off = 1; off < 64; off <<= 1) {
            m0 = fmaxf(m0, __shfl_xor(m0, off));
            m1 = fmaxf(m1, __shfl_xor(m1, off));
            m2 = fmaxf(m2, __shfl_xor(m2, off));
            m3 = fmaxf(m3, __shfl_xor(m3, off));
        }
        const float e0 = exp_np(a0 - m0);
        const float e1 = exp_np(a1 - m1);
        const float e2 = exp_np(a2 - m2);
        const float e3 = exp_np(a3 - m3);
        float s0 = 0.f, s1 = 0.f, s2 = 0.f, s3 = 0.f;
        #pragma unroll
        for (int t = 0; t < 64; ++t) {
            s0 = s0 + __shfl(e0, t);
            s1 = s1 + __shfl(e1, t);
            s2 = s2 + __shfl(e2, t);
            s3 = s3 + __shfl(e3, t);
        }
        KpT[(kq << 2) + 0][m] = e0 / s0;
        KpT[(kq << 2) + 1][m] = e1 / s1;
        KpT[(kq << 2) + 2][m] = e2 / s2;
        KpT[(kq << 2) + 3][m] = e3 / s3;
    } else {
        const int q = __builtin_amdgcn_readfirstlane(wid - 8);
        const int nm = lane;
        const float* wqq = Wq + (q << 2);
        const float* wvq = Wv + (q << 3);
        float a0 = 0.f, a1 = 0.f, a2 = 0.f, a3 = 0.f;
        float b0 = 0.f, b1 = 0.f, b2 = 0.f, b3 = 0.f, b4 = 0.f, b5 = 0.f, b6 = 0.f, b7 = 0.f;
        #pragma unroll 4
        for (int d = 0; d < Dn; ++d) {
            const float ff = fT[d][nm];
            const float cc = cT[d][nm];
            const float* wr = wqq + d * Dn;
            const float* ur = wvq + d * Mn;
            const float w0 = wr[0], w1 = wr[1], w2 = wr[2], w3 = wr[3];
            const float u0 = ur[0], u1 = ur[1], u2 = ur[2], u3 = ur[3];
            const float u4 = ur[4], u5 = ur[5], u6 = ur[6], u7 = ur[7];
            a0 = a0 + ff * w0;  a1 = a1 + ff * w1;  a2 = a2 + ff * w2;  a3 = a3 + ff * w3;
            b0 = b0 + cc * u0;  b1 = b1 + cc * u1;  b2 = b2 + cc * u2;  b3 = b3 + cc * u3;
            b4 = b4 + cc * u4;  b5 = b5 + cc * u5;  b6 = b6 + cc * u6;  b7 = b7 + cc * u7;
        }
        QmT[(q << 2) + 0][nm] = a0;
        QmT[(q << 2) + 1][nm] = a1;
        QmT[(q << 2) + 2][nm] = a2;
        QmT[(q << 2) + 3][nm] = a3;
        float4 r0; r0.x = b0; r0.y = b1; r0.z = b2; r0.w = b3;
        float4 r1; r1.x = b4; r1.y = b5; r1.z = b6; r1.w = b7;
        *reinterpret_cast<float4*>(&VwS[nm][(q << 3) + 0]) = r0;
        *reinterpret_cast<float4*>(&VwS[nm][(q << 3) + 4]) = r1;
    }
    __syncthreads();

    if (tid < 512) {
        const int k = tid >> 4, v4 = (tid & 15) << 2;
        float a0 = 0.f, a1 = 0.f, a2 = 0.f, a3 = 0.f;
        for (int m = 0; m < Mn; ++m) {
            const float kk = KpT[k][m];
            const float4 vv = *reinterpret_cast<const float4*>(&VwS[m][v4]);
            a0 = a0 + kk * vv.x;  a1 = a1 + kk * vv.y;  a2 = a2 + kk * vv.z;  a3 = a3 + kk * vv.w;
        }
        float4 r; r.x = a0; r.y = a1; r.z = a2; r.w = a3;
        *reinterpret_cast<float4*>(&lamS[k][v4]) = r;
    }
    __syncthreads();

    {
        const int n = tid >> 4, v4 = (tid & 15) << 2;
        float a0 = 0.f, a1 = 0.f, a2 = 0.f, a3 = 0.f;
        for (int k = 0; k < Dn; ++k) {
            const float qq = QmT[k][n];
            const float4 lv = *reinterpret_cast<const float4*>(&lamS[k][v4]);
            a0 = a0 + qq * lv.x;  a1 = a1 + qq * lv.y;  a2 = a2 + qq * lv.z;  a3 = a3 + qq * lv.w;
        }
        float4 r; r.x = a0; r.y = a1; r.z = a2; r.w = a3;
        *reinterpret_cast<float4*>(&VwS[n][v4]) = r;
    }
    __syncthreads();

    {
        const int g = tid & 15;
        const int n = tid >> 4;
        const float4 s4 = *reinterpret_cast<const float4*>(&VwS[n][g << 2]);
        unsigned su0 = f2u(s4.x), su1 = f2u(s4.y), su2 = f2u(s4.z), su3 = f2u(s4.w);
        unsigned avail = 0xFu;
        float val0 = 0.f, myval = 0.f;
        int   myidx = 0;
        #pragma unroll
        for (int t = 0; t < TK; ++t) {
            unsigned bu = 0u; int bm = 64;
            if ((avail & 1u) && su0 > bu) { bu = su0; bm = (g << 2) + 0; }
            if ((avail & 2u) && su1 > bu) { bu = su1; bm = (g << 2) + 1; }
            if ((avail & 4u) && su2 > bu) { bu = su2; bm = (g << 2) + 2; }
            if ((avail & 8u) && su3 > bu) { bu = su3; bm = (g << 2) + 3; }
            #pragma unroll
            for (int off = 1; off <= 8; off <<= 1) {
                const unsigned ou = __shfl_xor(bu, off);
                const int      om = __shfl_xor(bm, off);
                if (ou > bu || (ou == bu && om < bm)) { bu = ou; bm = om; }
            }
            const float bv = u2f(bu);
            if (t == 0) val0 = bv;
            if (g == t) { myval = bv; myidx = bm; }
            if ((bm >> 2) == g) avail &= ~(1u << (bm & 3));
        }
        const float ev_own = (g < TK) ? exp_np(myval - val0) : 0.f;
        float s = 0.f;
        #pragma unroll
        for (int t = 0; t < TK; ++t) {
            const float e = __shfl(ev_own, (lane & 48) + t);
            s = s + e;
        }
        if (g < TK) { topw[n][g] = ev_own / s; topi[n][g] = myidx; }
    }
    __syncthreads();

    float* ob = out + (size_t)b * (Nn * TK * Dn);
    constexpr int TOT4 = Nn * TK * Dn / 4;
    for (int i = tid; i < TOT4; i += 1024) {
        const int n = i / (TK * Dn / 4);
        const int r = i - n * (TK * Dn / 4);
        const int t = r >> 3;
        const int d4 = (r & 7) << 2;
        const float w = topw[n][t];
        const int m = topi[n][t];
        const float f0 = fT[d4 + 0][n];
        const float f1 = fT[d4 + 1][n];
        const float f2 = fT[d4 + 2][n];
        const float f3 = fT[d4 + 3][n];
        const float4 c4 = *reinterpret_cast<const float4*>(&c_lds[m][d4]);
        float4 o;
        { const float vx = f0 * c4.x; o.x = w * vx; }
        { const float vy = f1 * c4.y; o.y = w * vy; }
        { const float vz = f2 * c4.z; o.z = w * vz; }
        { const float vw = f3 * c4.w; o.w = w * vw; }
        reinterpret_cast<float4*>(ob)[i] = o;
    }
}

extern "C" void kernel_launch(void* const* d_in, const int* in_sizes, int n_in,
                              void* d_out, int out_size, void* d_ws, size_t ws_size,
                              hipStream_t stream) {
    const float* fv = (const float*)d_in[0];   // featureVec [256,64,32]
    const float* cv = (const float*)d_in[1];   // contextVec [256,64,32]
    const float* Wq = (const float*)d_in[2];   // [32,32]
    const float* Wk = (const float*)d_in[3];   // [32,32]
    const float* Wv = (const float*)d_in[4];   // [32,64]
    float* out = (float*)d_out;                // [256, 640, 32]

    const size_t ws_needed = (size_t)Bn * 4096 * sizeof(float);   // 4 MB
    if (ws_size >= ws_needed) {
        float* ws = (float*)d_ws;
        lam_kernel<<<Bn, 1024, 0, stream>>>(fv, cv, Wq, Wk, Wv, ws);
        out_kernel<<<Bn * 4, 256, 0, stream>>>(fv, cv, ws, out);
    } else {
        sparse_lambda_attn_mono<<<Bn, 1024, 0, stream>>>(fv, cv, Wq, Wk, Wv, out);
    }
}

// Round 11
// 29.570 us; speedup vs baseline: 1.2187x; 1.2187x over previous
//
#include <hip/hip_runtime.h>
#include <math.h>

// Problem constants: B=256, N=64, M=64, d=32, TOPK=10
constexpr int Bn = 256;
constexpr int Nn = 64;
constexpr int Mn = 64;
constexpr int Dn = 32;
constexpr int TK = 10;
constexpr int NT = 512;        // threads per block (8 waves)
constexpr int NBLK = Bn * 2;   // 2 blocks per batch, 32 output rows each

// Correctly-rounded fp32 exp via fp64 (matches np within <=0.5 ulp)
__device__ __forceinline__ float exp_np(float x) {
    return (float)exp((double)x);
}
// Monotone fp32 -> uint32 order map (weights finite; no NaNs)
__device__ __forceinline__ unsigned int f2u(float f) {
    unsigned int b = __float_as_uint(f);
    return (b & 0x80000000u) ? ~b : (b | 0x80000000u);
}
__device__ __forceinline__ float u2f(unsigned int u) {
    return __uint_as_float((u & 0x80000000u) ? (u ^ 0x80000000u) : ~u);
}

__global__ __launch_bounds__(NT) void sparse_lambda_attn_kernel(
    const float* __restrict__ fv,   // [B,N,D]
    const float* __restrict__ cv,   // [B,M,D]
    const float* __restrict__ Wq,   // [D,D]
    const float* __restrict__ Wk,   // [D,D]
    const float* __restrict__ Wv,   // [D,M]
    float* __restrict__ out)        // [B, N*TK, D]
{
    // Replicate numpy fp32 semantics: NO fma contraction anywhere in this kernel.
    #pragma clang fp contract(off)

    __shared__ float cT[Dn][65];     // 8.1 KB [d][m]
    __shared__ float fTh[Dn][33];    // 4.1 KB [d][n_local] (this block's 32 rows)
    __shared__ float c_row[Mn][36];  // 9 KB   [m][d] (output gather)
    __shared__ float wqS[Dn][Dn];    // 4 KB
    __shared__ float wkS[Dn][Dn];    // 4 KB
    __shared__ float wvS[Dn][Mn];    // 8 KB
    __shared__ float KpT[Dn][65];    // 8.1 KB [k][m] K probabilities
    __shared__ float QmT[Dn][33];    // 4.1 KB [k][n_local]
    __shared__ float Vs[Mn][68];     // 17 KB  [m][v]
    __shared__ float lamS[Dn][68];   // 8.5 KB [k][v]
    __shared__ float topw[32][TK];   // 1.25 KB
    __shared__ int   topi[32][TK];   // 1.25 KB
    // total ~77.3 KB -> 2 blocks/CU

    const int bid  = blockIdx.x;
    const int b    = bid >> 1;
    const int n0   = (bid & 1) << 5;   // 0 or 32: this block's row range
    const int tid  = threadIdx.x;
    const int lane = tid & 63;
    const int wid  = tid >> 6;

    // ---- stage: c (full), f (32 rows), Wq/Wk/Wv -> LDS ----
    {
        const float4 v = reinterpret_cast<const float4*>(cv + (size_t)b * Mn * Dn)[tid];
        const int m = tid >> 3, d4 = (tid & 7) << 2;
        *reinterpret_cast<float4*>(&c_row[m][d4]) = v;
        cT[d4 + 0][m] = v.x; cT[d4 + 1][m] = v.y; cT[d4 + 2][m] = v.z; cT[d4 + 3][m] = v.w;
    }
    if (tid < 256) {
        const float4 v = reinterpret_cast<const float4*>(fv + (size_t)b * Nn * Dn)[(n0 << 3) + tid];
        const int n = tid >> 3, d4 = (tid & 7) << 2;
        fTh[d4 + 0][n] = v.x; fTh[d4 + 1][n] = v.y; fTh[d4 + 2][n] = v.z; fTh[d4 + 3][n] = v.w;
    }
    {
        if (tid < 256) reinterpret_cast<float4*>(&wqS[0][0])[tid] = reinterpret_cast<const float4*>(Wq)[tid];
        else           reinterpret_cast<float4*>(&wkS[0][0])[tid - 256] = reinterpret_cast<const float4*>(Wk)[tid - 256];
        reinterpret_cast<float4*>(&wvS[0][0])[tid] = reinterpret_cast<const float4*>(Wv)[tid];
    }
    __syncthreads();

    // ---- Phase A (one barrier): waves 0-3 = K logits + FULL softmax (wave-local);
    //      waves 4-7 = V (16 cols) + Q (8 cols x 32 rows). np-exact chains throughout.
    if (wid < 4) {
        const int c0 = wid << 3;   // K columns c0..c0+7; lane = m
        const int m = lane;
        float a0=0.f,a1=0.f,a2=0.f,a3=0.f,a4=0.f,a5=0.f,a6=0.f,a7=0.f;
        #pragma unroll 8
        for (int d = 0; d < Dn; ++d) {
            const float cc = cT[d][m];
            const float4 w0 = *reinterpret_cast<const float4*>(&wkS[d][c0]);
            const float4 w1 = *reinterpret_cast<const float4*>(&wkS[d][c0 + 4]);
            a0 = a0 + cc * w0.x;  a1 = a1 + cc * w0.y;  a2 = a2 + cc * w0.z;  a3 = a3 + cc * w0.w;
            a4 = a4 + cc * w1.x;  a5 = a5 + cc * w1.y;  a6 = a6 + cc * w1.z;  a7 = a7 + cc * w1.w;
        }
        // column max via xor shuffle trees (fmax exactly order-independent)
        float m0=a0,m1=a1,m2=a2,m3=a3,m4=a4,m5=a5,m6=a6,m7=a7;
        #pragma unroll
        for (int off = 1; off < 64; off <<= 1) {
            m0 = fmaxf(m0, __shfl_xor(m0, off));
            m1 = fmaxf(m1, __shfl_xor(m1, off));
            m2 = fmaxf(m2, __shfl_xor(m2, off));
            m3 = fmaxf(m3, __shfl_xor(m3, off));
            m4 = fmaxf(m4, __shfl_xor(m4, off));
            m5 = fmaxf(m5, __shfl_xor(m5, off));
            m6 = fmaxf(m6, __shfl_xor(m6, off));
            m7 = fmaxf(m7, __shfl_xor(m7, off));
        }
        // exp (np: elementwise), stash e to LDS
        const float e0 = exp_np(a0 - m0), e1 = exp_np(a1 - m1);
        const float e2 = exp_np(a2 - m2), e3 = exp_np(a3 - m3);
        const float e4 = exp_np(a4 - m4), e5 = exp_np(a5 - m5);
        const float e6 = exp_np(a6 - m6), e7 = exp_np(a7 - m7);
        KpT[c0 + 0][m] = e0; KpT[c0 + 1][m] = e1;
        KpT[c0 + 2][m] = e2; KpT[c0 + 3][m] = e3;
        KpT[c0 + 4][m] = e4; KpT[c0 + 5][m] = e5;
        KpT[c0 + 6][m] = e6; KpT[c0 + 7][m] = e7;
        // ascending-m ordered sum (np.sum order), one lane per column (wave-local: in-order LDS)
        float s = 0.f;
        if (lane < 8) {
            const int col = c0 + lane;
            for (int mm = 0; mm < Mn; ++mm) s = s + KpT[col][mm];
        }
        // true division, final probabilities
        const float s0 = __shfl(s, 0), s1 = __shfl(s, 1), s2 = __shfl(s, 2), s3 = __shfl(s, 3);
        const float s4 = __shfl(s, 4), s5 = __shfl(s, 5), s6 = __shfl(s, 6), s7 = __shfl(s, 7);
        KpT[c0 + 0][m] = e0 / s0; KpT[c0 + 1][m] = e1 / s1;
        KpT[c0 + 2][m] = e2 / s2; KpT[c0 + 3][m] = e3 / s3;
        KpT[c0 + 4][m] = e4 / s4; KpT[c0 + 5][m] = e5 / s5;
        KpT[c0 + 6][m] = e6 / s6; KpT[c0 + 7][m] = e7 / s7;
    } else {
        const int q  = wid - 4;
        const int v0 = q << 4;                              // V columns v0..v0+15; lane = m
        const int m  = lane;
        const int nl = lane & 31;                           // Q: lanes 0-31 rows, two col-quads
        const int qc = (q << 3) + ((lane >> 5) << 2);       // Q columns qc..qc+3
        float b0=0.f,b1=0.f,b2=0.f,b3=0.f,b4=0.f,b5=0.f,b6=0.f,b7=0.f;
        float b8=0.f,b9=0.f,bA=0.f,bB=0.f,bC=0.f,bD=0.f,bE=0.f,bF=0.f;
        float q0=0.f,q1=0.f,q2=0.f,q3=0.f;
        #pragma unroll 4
        for (int d = 0; d < Dn; ++d) {
            const float cc = cT[d][m];
            const float ff = fTh[d][nl];
            const float4 u0 = *reinterpret_cast<const float4*>(&wvS[d][v0]);
            const float4 u1 = *reinterpret_cast<const float4*>(&wvS[d][v0 + 4]);
            const float4 u2 = *reinterpret_cast<const float4*>(&wvS[d][v0 + 8]);
            const float4 u3 = *reinterpret_cast<const float4*>(&wvS[d][v0 + 12]);
            const float4 wq4 = *reinterpret_cast<const float4*>(&wqS[d][qc]);
            b0 = b0 + cc * u0.x;  b1 = b1 + cc * u0.y;  b2 = b2 + cc * u0.z;  b3 = b3 + cc * u0.w;
            b4 = b4 + cc * u1.x;  b5 = b5 + cc * u1.y;  b6 = b6 + cc * u1.z;  b7 = b7 + cc * u1.w;
            b8 = b8 + cc * u2.x;  b9 = b9 + cc * u2.y;  bA = bA + cc * u2.z;  bB = bB + cc * u2.w;
            bC = bC + cc * u3.x;  bD = bD + cc * u3.y;  bE = bE + cc * u3.z;  bF = bF + cc * u3.w;
            q0 = q0 + ff * wq4.x; q1 = q1 + ff * wq4.y; q2 = q2 + ff * wq4.z; q3 = q3 + ff * wq4.w;
        }
        float4 r;
        r.x=b0; r.y=b1; r.z=b2; r.w=b3; *reinterpret_cast<float4*>(&Vs[m][v0 +  0]) = r;
        r.x=b4; r.y=b5; r.z=b6; r.w=b7; *reinterpret_cast<float4*>(&Vs[m][v0 +  4]) = r;
        r.x=b8; r.y=b9; r.z=bA; r.w=bB; *reinterpret_cast<float4*>(&Vs[m][v0 +  8]) = r;
        r.x=bC; r.y=bD; r.z=bE; r.w=bF; *reinterpret_cast<float4*>(&Vs[m][v0 + 12]) = r;
        QmT[qc + 0][nl] = q0;
        QmT[qc + 1][nl] = q1;
        QmT[qc + 2][nl] = q2;
        QmT[qc + 3][nl] = q3;
    }
    __syncthreads();

    // ---- lam[k][v] = sum_m K[m][k]*V[m][v]: (k, v4), 512 threads, ascending m ----
    {
        const int k = tid >> 4, v4 = (tid & 15) << 2;
        float a0 = 0.f, a1 = 0.f, a2 = 0.f, a3 = 0.f;
        for (int m = 0; m < Mn; ++m) {
            const float kk = KpT[k][m];
            const float4 vv = *reinterpret_cast<const float4*>(&Vs[m][v4]);
            a0 = a0 + kk * vv.x;  a1 = a1 + kk * vv.y;  a2 = a2 + kk * vv.z;  a3 = a3 + kk * vv.w;
        }
        float4 r; r.x = a0; r.y = a1; r.z = a2; r.w = a3;
        *reinterpret_cast<float4*>(&lamS[k][v4]) = r;
    }
    __syncthreads();

    // ---- weight (np-exact ascending-k) FUSED with top-10 selection + softmax ----
    {
        const int nl = tid >> 4;     // 0..31 local row
        const int g  = tid & 15;
        const int v4 = g << 2;
        float a0 = 0.f, a1 = 0.f, a2 = 0.f, a3 = 0.f;
        for (int k = 0; k < Dn; ++k) {
            const float qq = QmT[k][nl];
            const float4 lv = *reinterpret_cast<const float4*>(&lamS[k][v4]);
            a0 = a0 + qq * lv.x;  a1 = a1 + qq * lv.y;  a2 = a2 + qq * lv.z;  a3 = a3 + qq * lv.w;
        }

        unsigned su0 = f2u(a0), su1 = f2u(a1), su2 = f2u(a2), su3 = f2u(a3);
        unsigned avail = 0xFu;
        float val0 = 0.f, myval = 0.f;
        int   myidx = 0;

        #pragma unroll
        for (int t = 0; t < TK; ++t) {
            unsigned bu = 0u; int bm = 64;
            if ((avail & 1u) && su0 > bu) { bu = su0; bm = (g << 2) + 0; }
            if ((avail & 2u) && su1 > bu) { bu = su1; bm = (g << 2) + 1; }
            if ((avail & 4u) && su2 > bu) { bu = su2; bm = (g << 2) + 2; }
            if ((avail & 8u) && su3 > bu) { bu = su3; bm = (g << 2) + 3; }
            #pragma unroll
            for (int off = 1; off <= 8; off <<= 1) {
                const unsigned ou = __shfl_xor(bu, off);
                const int      om = __shfl_xor(bm, off);
                if (ou > bu || (ou == bu && om < bm)) { bu = ou; bm = om; }
            }
            const float bv = u2f(bu);
            if (t == 0) val0 = bv;
            if (g == t) { myval = bv; myidx = bm; }
            if ((bm >> 2) == g) avail &= ~(1u << (bm & 3));
        }

        const float ev_own = (g < TK) ? exp_np(myval - val0) : 0.f;
        float s = 0.f;
        #pragma unroll
        for (int t = 0; t < TK; ++t) {
            const float e = __shfl(ev_own, (lane & 48) + t);
            s = s + e;
        }
        if (g < TK) {
            topw[nl][g] = ev_own / s;
            topi[nl][g] = myidx;
        }
    }
    __syncthreads();

    // ---- output: out[b][(n0+n)*TK+t][d] = w * (f[n][d]*c[idx][d]), f4 coalesced ----
    float* ob = out + (size_t)b * (Nn * TK * Dn) + (size_t)n0 * (TK * Dn);
    #pragma unroll
    for (int p = 0; p < 5; ++p) {
        const int i = tid + (p << 9);        // 0..2559 f4 (32 rows x 800 floats)
        const int n = i / 80;
        const int r = i - n * 80;
        const int t = r >> 3;
        const int d4 = (r & 7) << 2;
        const float w = topw[n][t];
        const int m = topi[n][t];
        const float f0 = fTh[d4 + 0][n];
        const float f1 = fTh[d4 + 1][n];
        const float f2 = fTh[d4 + 2][n];
        const float f3 = fTh[d4 + 3][n];
        const float4 cr = *reinterpret_cast<const float4*>(&c_row[m][d4]);
        float4 o;
        { const float vx = f0 * cr.x; o.x = w * vx; }
        { const float vy = f1 * cr.y; o.y = w * vy; }
        { const float vz = f2 * cr.z; o.z = w * vz; }
        { const float vw = f3 * cr.w; o.w = w * vw; }
        reinterpret_cast<float4*>(ob)[i] = o;
    }
}

extern "C" void kernel_launch(void* const* d_in, const int* in_sizes, int n_in,
                              void* d_out, int out_size, void* d_ws, size_t ws_size,
                              hipStream_t stream) {
    const float* fv = (const float*)d_in[0];   // featureVec [256,64,32]
    const float* cv = (const float*)d_in[1];   // contextVec [256,64,32]
    const float* Wq = (const float*)d_in[2];   // [32,32]
    const float* Wk = (const float*)d_in[3];   // [32,32]
    const float* Wv = (const float*)d_in[4];   // [32,64]
    float* out = (float*)d_out;                // [256, 640, 32]

    sparse_lambda_attn_kernel<<<NBLK, NT, 0, stream>>>(fv, cv, Wq, Wk, Wv, out);
}

// Round 12
// 24.192 us; speedup vs baseline: 1.4897x; 1.2223x over previous
//
#include <hip/hip_runtime.h>
#include <math.h>

// Problem constants: B=256, N=64, M=64, d=32, TOPK=10
constexpr int Bn = 256;
constexpr int Nn = 64;
constexpr int Mn = 64;
constexpr int Dn = 32;
constexpr int TK = 10;
constexpr int NT = 1024;   // 16 waves

// Correctly-rounded fp32 exp via fp64 (matches np within <=0.5 ulp)
__device__ __forceinline__ float exp_np(float x) {
    return (float)exp((double)x);
}
// Monotone fp32 -> uint32 order map (weights finite; no NaNs)
__device__ __forceinline__ unsigned int f2u(float f) {
    unsigned int b = __float_as_uint(f);
    return (b & 0x80000000u) ? ~b : (b | 0x80000000u);
}
__device__ __forceinline__ float u2f(unsigned int u) {
    return __uint_as_float((u & 0x80000000u) ? (u ^ 0x80000000u) : ~u);
}

__global__ __launch_bounds__(NT) void sparse_lambda_attn_kernel(
    const float* __restrict__ fv,   // [B,N,D]
    const float* __restrict__ cv,   // [B,M,D]
    const float* __restrict__ Wq,   // [D,D]
    const float* __restrict__ Wk,   // [D,D]
    const float* __restrict__ Wv,   // [D,M]
    float* __restrict__ out)        // [B, N*TK, D]
{
    // Replicate numpy fp32 semantics: NO fma contraction anywhere in this kernel.
    #pragma clang fp contract(off)

    __shared__ float fT[Dn][65];     // 8.1 KB [d][n]
    __shared__ float cT[Dn][65];     // 8.1 KB [d][m]
    __shared__ float c_row[Mn][36];  // 9 KB   [m][d] (output gather)
    __shared__ float KpT[Dn][68];    // 8.5 KB [k][m] K probabilities
    __shared__ float QmT[Dn][68];    // 8.5 KB [k][n]
    __shared__ float Vs[Mn][68];     // 17 KB  [m][v]
    __shared__ float lamS[Dn][68];   // 8.5 KB [k][v]
    __shared__ float topw[Nn][TK];   // 2.5 KB
    __shared__ int   topi[Nn][TK];   // 2.5 KB
    // total ~72.7 KB

    const int b    = blockIdx.x;
    const int tid  = threadIdx.x;
    const int lane = tid & 63;
    const int wid  = tid >> 6;

    // ---- stage: f -> fT, c -> c_row + cT (coalesced f4 global reads) ----
    if (tid < 512) {
        const float4 v = reinterpret_cast<const float4*>(fv + (size_t)b * Nn * Dn)[tid];
        const int n = tid >> 3, d4 = (tid & 7) << 2;
        fT[d4 + 0][n] = v.x; fT[d4 + 1][n] = v.y; fT[d4 + 2][n] = v.z; fT[d4 + 3][n] = v.w;
    } else {
        const int t = tid - 512;
        const float4 v = reinterpret_cast<const float4*>(cv + (size_t)b * Mn * Dn)[t];
        const int m = t >> 3, d4 = (t & 7) << 2;
        *reinterpret_cast<float4*>(&c_row[m][d4]) = v;
        cT[d4 + 0][m] = v.x; cT[d4 + 1][m] = v.y; cT[d4 + 2][m] = v.z; cT[d4 + 3][m] = v.w;
    }
    __syncthreads();

    // ---- Phase A (one barrier):
    //   waves 0-7:  K cols 4w..4w+3 + FULL wave-local softmax (proven in r11)
    //   waves 8-15: Q cols 4q..4q+3 (lane=n) AND V cols 8q..8q+7 (lane=m)
    //   W matrices via wave-uniform pointers -> scalar cache (s_load, proven in r9)
    if (wid < 8) {
        const int kq = __builtin_amdgcn_readfirstlane(wid);
        const int m = lane;
        const float* wkq = Wk + (kq << 2);
        float a0 = 0.f, a1 = 0.f, a2 = 0.f, a3 = 0.f;
        #pragma unroll 8
        for (int d = 0; d < Dn; ++d) {
            const float cc = cT[d][m];
            const float* wr = wkq + d * Dn;
            const float w0 = wr[0], w1 = wr[1], w2 = wr[2], w3 = wr[3];
            a0 = a0 + cc * w0;  a1 = a1 + cc * w1;  a2 = a2 + cc * w2;  a3 = a3 + cc * w3;
        }
        // column max via xor shuffle trees (fmax exactly order-independent)
        float m0 = a0, m1 = a1, m2 = a2, m3 = a3;
        #pragma unroll
        for (int off = 1; off < 64; off <<= 1) {
            m0 = fmaxf(m0, __shfl_xor(m0, off));
            m1 = fmaxf(m1, __shfl_xor(m1, off));
            m2 = fmaxf(m2, __shfl_xor(m2, off));
            m3 = fmaxf(m3, __shfl_xor(m3, off));
        }
        // exp (np: elementwise), stash to LDS
        const float e0 = exp_np(a0 - m0), e1 = exp_np(a1 - m1);
        const float e2 = exp_np(a2 - m2), e3 = exp_np(a3 - m3);
        KpT[(kq << 2) + 0][m] = e0;
        KpT[(kq << 2) + 1][m] = e1;
        KpT[(kq << 2) + 2][m] = e2;
        KpT[(kq << 2) + 3][m] = e3;
        // ascending-m ordered sum (np.sum order), one lane per column (wave-local)
        float s = 0.f;
        if (lane < 4) {
            const int col = (kq << 2) + lane;
            for (int mm = 0; mm < Mn; ++mm) s = s + KpT[col][mm];
        }
        const float s0 = __shfl(s, 0), s1 = __shfl(s, 1);
        const float s2 = __shfl(s, 2), s3 = __shfl(s, 3);
        // true division, final probabilities
        KpT[(kq << 2) + 0][m] = e0 / s0;
        KpT[(kq << 2) + 1][m] = e1 / s1;
        KpT[(kq << 2) + 2][m] = e2 / s2;
        KpT[(kq << 2) + 3][m] = e3 / s3;
    } else {
        const int q = __builtin_amdgcn_readfirstlane(wid - 8);
        const int nm = lane;
        const float* wqq = Wq + (q << 2);
        const float* wvq = Wv + (q << 3);
        float q0 = 0.f, q1 = 0.f, q2 = 0.f, q3 = 0.f;
        float b0 = 0.f, b1 = 0.f, b2 = 0.f, b3 = 0.f;
        float b4 = 0.f, b5 = 0.f, b6 = 0.f, b7 = 0.f;
        #pragma unroll 4
        for (int d = 0; d < Dn; ++d) {
            const float ff = fT[d][nm];
            const float cc = cT[d][nm];
            const float* wr = wqq + d * Dn;
            const float* ur = wvq + d * Mn;
            const float w0 = wr[0], w1 = wr[1], w2 = wr[2], w3 = wr[3];
            const float u0 = ur[0], u1 = ur[1], u2 = ur[2], u3 = ur[3];
            const float u4 = ur[4], u5 = ur[5], u6 = ur[6], u7 = ur[7];
            q0 = q0 + ff * w0;  q1 = q1 + ff * w1;  q2 = q2 + ff * w2;  q3 = q3 + ff * w3;
            b0 = b0 + cc * u0;  b1 = b1 + cc * u1;  b2 = b2 + cc * u2;  b3 = b3 + cc * u3;
            b4 = b4 + cc * u4;  b5 = b5 + cc * u5;  b6 = b6 + cc * u6;  b7 = b7 + cc * u7;
        }
        QmT[(q << 2) + 0][nm] = q0;
        QmT[(q << 2) + 1][nm] = q1;
        QmT[(q << 2) + 2][nm] = q2;
        QmT[(q << 2) + 3][nm] = q3;
        float4 r0; r0.x = b0; r0.y = b1; r0.z = b2; r0.w = b3;
        float4 r1; r1.x = b4; r1.y = b5; r1.z = b6; r1.w = b7;
        *reinterpret_cast<float4*>(&Vs[nm][(q << 3) + 0]) = r0;
        *reinterpret_cast<float4*>(&Vs[nm][(q << 3) + 4]) = r1;
    }
    __syncthreads();

    // ---- lam[k][v] = sum_m K[m][k]*V[m][v]: 512 threads, (k, v4), ascending m (r7 form) ----
    if (tid < 512) {
        const int k = tid >> 4, v4 = (tid & 15) << 2;
        float a0 = 0.f, a1 = 0.f, a2 = 0.f, a3 = 0.f;
        for (int m = 0; m < Mn; ++m) {
            const float kk = KpT[k][m];
            const float4 vv = *reinterpret_cast<const float4*>(&Vs[m][v4]);
            a0 = a0 + kk * vv.x;  a1 = a1 + kk * vv.y;  a2 = a2 + kk * vv.z;  a3 = a3 + kk * vv.w;
        }
        float4 r; r.x = a0; r.y = a1; r.z = a2; r.w = a3;
        *reinterpret_cast<float4*>(&lamS[k][v4]) = r;
    }
    __syncthreads();

    // ---- weight (np-exact ascending-k) FUSED with top-10 selection + softmax ----
    {
        const int nl = tid >> 4;     // 0..63
        const int g  = tid & 15;
        const int v4 = g << 2;
        float a0 = 0.f, a1 = 0.f, a2 = 0.f, a3 = 0.f;
        for (int k = 0; k < Dn; ++k) {
            const float qq = QmT[k][nl];
            const float4 lv = *reinterpret_cast<const float4*>(&lamS[k][v4]);
            a0 = a0 + qq * lv.x;  a1 = a1 + qq * lv.y;  a2 = a2 + qq * lv.z;  a3 = a3 + qq * lv.w;
        }

        unsigned su0 = f2u(a0), su1 = f2u(a1), su2 = f2u(a2), su3 = f2u(a3);
        unsigned avail = 0xFu;
        float val0 = 0.f, myval = 0.f;
        int   myidx = 0;

        #pragma unroll
        for (int t = 0; t < TK; ++t) {
            unsigned bu = 0u; int bm = 64;
            if ((avail & 1u) && su0 > bu) { bu = su0; bm = (g << 2) + 0; }
            if ((avail & 2u) && su1 > bu) { bu = su1; bm = (g << 2) + 1; }
            if ((avail & 4u) && su2 > bu) { bu = su2; bm = (g << 2) + 2; }
            if ((avail & 8u) && su3 > bu) { bu = su3; bm = (g << 2) + 3; }
            #pragma unroll
            for (int off = 1; off <= 8; off <<= 1) {
                const unsigned ou = __shfl_xor(bu, off);
                const int      om = __shfl_xor(bm, off);
                if (ou > bu || (ou == bu && om < bm)) { bu = ou; bm = om; }
            }
            const float bv = u2f(bu);
            if (t == 0) val0 = bv;
            if (g == t) { myval = bv; myidx = bm; }
            if ((bm >> 2) == g) avail &= ~(1u << (bm & 3));
        }

        const float ev_own = (g < TK) ? exp_np(myval - val0) : 0.f;
        float s = 0.f;
        #pragma unroll
        for (int t = 0; t < TK; ++t) {
            const float e = __shfl(ev_own, (lane & 48) + t);
            s = s + e;
        }
        if (g < TK) {
            topw[nl][g] = ev_own / s;
            topi[nl][g] = myidx;
        }
    }
    __syncthreads();

    // ---- output: out[b][n*TK+t][d] = w * (f[n][d]*c[idx][d]), f4-coalesced stores ----
    float* ob = out + (size_t)b * (Nn * TK * Dn);
    constexpr int TOT4 = Nn * TK * Dn / 4;   // 5120 float4 per batch
    #pragma unroll
    for (int p = 0; p < 5; ++p) {
        const int i = tid + (p << 10);
        const int n = i / 80;
        const int r = i - n * 80;
        const int t = r >> 3;
        const int d4 = (r & 7) << 2;
        const float w = topw[n][t];
        const int m = topi[n][t];
        const float f0 = fT[d4 + 0][n];
        const float f1 = fT[d4 + 1][n];
        const float f2 = fT[d4 + 2][n];
        const float f3 = fT[d4 + 3][n];
        const float4 cr = *reinterpret_cast<const float4*>(&c_row[m][d4]);
        float4 o;
        { const float vx = f0 * cr.x; o.x = w * vx; }
        { const float vy = f1 * cr.y; o.y = w * vy; }
        { const float vz = f2 * cr.z; o.z = w * vz; }
        { const float vw = f3 * cr.w; o.w = w * vw; }
        reinterpret_cast<float4*>(ob)[i] = o;
    }
}

extern "C" void kernel_launch(void* const* d_in, const int* in_sizes, int n_in,
                              void* d_out, int out_size, void* d_ws, size_t ws_size,
                              hipStream_t stream) {
    const float* fv = (const float*)d_in[0];   // featureVec [256,64,32]
    const float* cv = (const float*)d_in[1];   // contextVec [256,64,32]
    const float* Wq = (const float*)d_in[2];   // [32,32]
    const float* Wk = (const float*)d_in[3];   // [32,32]
    const float* Wv = (const float*)d_in[4];   // [32,64]
    float* out = (float*)d_out;                // [256, 640, 32]

    sparse_lambda_attn_kernel<<<Bn, NT, 0, stream>>>(fv, cv, Wq, Wk, Wv, out);
}